// Round 1
// baseline (870.210 us; speedup 1.0000x reference)
//
#include <hip/hip_runtime.h>
#include <hip/hip_bf16.h>
#include <math.h>

#define N_ROWS 65536
#define K_EMB  8192
#define D_DIM  64
#define BR     128   // rows per block
#define BKT    128   // embeddings per k-tile
#define TM     8
#define TK     8

// ---------------- e_sq precompute: one wave per embedding row ----------------
__global__ void esq_kernel(const float* __restrict__ emb, float* __restrict__ es) {
    int k    = blockIdx.x * 4 + (threadIdx.x >> 6);   // 4 rows per 256-thr block
    int lane = threadIdx.x & 63;
    float v = emb[(size_t)k * D_DIM + lane];
    float s = v * v;
    #pragma unroll
    for (int off = 32; off >= 1; off >>= 1) s += __shfl_down(s, off, 64);
    if (lane == 0) es[k] = s;
}

// ---------------- main VQ kernel ----------------
__global__ __launch_bounds__(256, 2)
void vq_main(const float* __restrict__ z, const float* __restrict__ emb,
             const float* __restrict__ es_g, float* __restrict__ out,
             double* __restrict__ loss_acc) {
    __shared__ float zT[D_DIM * BR];   // zT[d*128 + rot(m,d)]
    __shared__ float eT[D_DIM * BKT];  // eT[d*128 + rot(k,d)]
    __shared__ float zs_lds[BR];
    __shared__ int   bestk[BR];

    const int t  = threadIdx.x;
    const int tx = t & 15;        // k-group
    const int ty = t >> 4;        // row-group
    const int m0 = blockIdx.x * BR;

    // ---- stage z tile: transposed + rotated, coalesced global reads ----
    #pragma unroll
    for (int i = 0; i < 8; i++) {
        int r = i * 16 + ty;                       // local row 0..127
        float4 v = *reinterpret_cast<const float4*>(&z[(size_t)(m0 + r) * D_DIM + 4 * tx]);
        int col  = (r + 4 * tx) & 127;             // rotate by 4*(d>>2), d>>2 == tx
        int base = (4 * tx) * BR + col;
        zT[base]           = v.x;
        zT[base + BR]      = v.y;
        zT[base + 2 * BR]  = v.z;
        zT[base + 3 * BR]  = v.w;
    }
    __syncthreads();

    // ---- z_sq per row (sequential over d, common-mode per row) ----
    if (t < BR) {
        float s = 0.f;
        #pragma unroll 8
        for (int d = 0; d < D_DIM; d++) {
            int col = (t + 4 * (d >> 2)) & 127;
            float v = zT[d * BR + col];
            s = fmaf(v, v, s);
        }
        zs_lds[t] = s;
    }
    __syncthreads();

    float zsr[TM];
    #pragma unroll
    for (int i = 0; i < TM; i++) zsr[i] = zs_lds[ty * 8 + i];

    float bv[TM];
    int   bi[TM];
    #pragma unroll
    for (int i = 0; i < TM; i++) { bv[i] = INFINITY; bi[i] = 0; }

    // ---- main loop over embedding tiles ----
    for (int kt = 0; kt < K_EMB; kt += BKT) {
        __syncthreads();   // previous tile's compute done before overwrite
        // stage e tile (transposed + rotated)
        #pragma unroll
        for (int i = 0; i < 8; i++) {
            int kr = i * 16 + ty;
            float4 v = *reinterpret_cast<const float4*>(&emb[(size_t)(kt + kr) * D_DIM + 4 * tx]);
            int col  = (kr + 4 * tx) & 127;
            int base = (4 * tx) * BKT + col;
            eT[base]            = v.x;
            eT[base + BKT]      = v.y;
            eT[base + 2 * BKT]  = v.z;
            eT[base + 3 * BKT]  = v.w;
        }
        float esr[TK];
        #pragma unroll
        for (int j = 0; j < TK; j++) esr[j] = es_g[kt + tx * 8 + j];
        __syncthreads();

        // accumulate dot products: acc[i][j] = z[row_i] . e[col_j]
        float acc[TM][TK];
        #pragma unroll
        for (int i = 0; i < TM; i++)
            #pragma unroll
            for (int j = 0; j < TK; j++) acc[i][j] = 0.f;

        for (int d4 = 0; d4 < 16; d4++) {
            int shift = 4 * d4;
            int zc0 = (ty * 8 + shift) & 127;
            int zc1 = (ty * 8 + 4 + shift) & 127;
            int ec0 = (tx * 8 + shift) & 127;
            int ec1 = (tx * 8 + 4 + shift) & 127;
            #pragma unroll
            for (int j = 0; j < 4; j++) {
                int dr = (4 * d4 + j) * 128;
                float4 za0 = *reinterpret_cast<const float4*>(&zT[dr + zc0]);
                float4 za1 = *reinterpret_cast<const float4*>(&zT[dr + zc1]);
                float4 eb0 = *reinterpret_cast<const float4*>(&eT[dr + ec0]);
                float4 eb1 = *reinterpret_cast<const float4*>(&eT[dr + ec1]);
                float zv[8] = {za0.x, za0.y, za0.z, za0.w, za1.x, za1.y, za1.z, za1.w};
                float ev[8] = {eb0.x, eb0.y, eb0.z, eb0.w, eb1.x, eb1.y, eb1.z, eb1.w};
                #pragma unroll
                for (int i = 0; i < TM; i++)
                    #pragma unroll
                    for (int jj = 0; jj < TK; jj++)
                        acc[i][jj] = fmaf(zv[i], ev[jj], acc[i][jj]);
            }
        }

        // best update: d2 = (z_sq - 2*dot) + e_sq, reference rounding order
        #pragma unroll
        for (int j = 0; j < TK; j++) {
            int   kg = kt + tx * 8 + j;
            float es = esr[j];
            #pragma unroll
            for (int i = 0; i < TM; i++) {
                float val = fmaf(-2.0f, acc[i][j], zsr[i]) + es;
                if (val < bv[i]) { bv[i] = val; bi[i] = kg; }
            }
        }
    }

    // ---- reduce over the 16 tx lanes sharing each row ----
    #pragma unroll
    for (int i = 0; i < TM; i++) {
        float v  = bv[i];
        int   ix = bi[i];
        #pragma unroll
        for (int off = 1; off < 16; off <<= 1) {
            float ov = __shfl_xor(v, off, 16);
            int   oi = __shfl_xor(ix, off, 16);
            if (ov < v || (ov == v && oi < ix)) { v = ov; ix = oi; }
        }
        if (tx == 0) bestk[ty * 8 + i] = ix;
    }
    __syncthreads();

    // ---- epilogue: gather, straight-through write, loss, indices ----
    double ls = 0.0;
    #pragma unroll
    for (int i = 0; i < 8; i++) {
        int r  = i * 16 + ty;
        int bk = bestk[r];
        float4 q = *reinterpret_cast<const float4*>(&emb[(size_t)bk * D_DIM + 4 * tx]);
        int col  = (r + 4 * tx) & 127;
        int base = (4 * tx) * BR + col;
        float zx = zT[base];
        float zy = zT[base + BR];
        float zz = zT[base + 2 * BR];
        float zw = zT[base + 3 * BR];
        // straight-through: z + (q - z), fp32 op order as reference
        float4 o;
        o.x = zx + (q.x - zx);
        o.y = zy + (q.y - zy);
        o.z = zz + (q.z - zz);
        o.w = zw + (q.w - zw);
        *reinterpret_cast<float4*>(&out[(size_t)(m0 + r) * D_DIM + 4 * tx]) = o;
        // loss: (z - q)^2 in fp32, accumulate in double
        float ax = zx - q.x, ay = zy - q.y, az = zz - q.z, aw = zw - q.w;
        ls += (double)(ax * ax) + (double)(ay * ay) + (double)(az * az) + (double)(aw * aw);
    }
    if (t < BR) {
        out[(size_t)N_ROWS * D_DIM + 2 + m0 + t] = (float)bestk[t];
    }
    // block loss reduction -> global atomic
    #pragma unroll
    for (int off = 32; off >= 1; off >>= 1) ls += __shfl_down(ls, off, 64);
    if ((t & 63) == 0) atomicAdd(loss_acc, ls);
}

// ---------------- finalize losses ----------------
__global__ void finalize_kernel(const double* __restrict__ acc, float* __restrict__ out) {
    double m = *acc / (double)((size_t)N_ROWS * D_DIM);
    out[(size_t)N_ROWS * D_DIM]     = (float)m;  // vq_loss
    out[(size_t)N_ROWS * D_DIM + 1] = (float)m;  // commitment_loss (identical value)
}

extern "C" void kernel_launch(void* const* d_in, const int* in_sizes, int n_in,
                              void* d_out, int out_size, void* d_ws, size_t ws_size,
                              hipStream_t stream) {
    const float* z   = (const float*)d_in[0];
    const float* emb = (const float*)d_in[1];
    float* out = (float*)d_out;

    double* lacc = (double*)d_ws;
    float*  es   = (float*)((char*)d_ws + 16);

    hipMemsetAsync(d_ws, 0, 16, stream);
    esq_kernel<<<K_EMB / 4, 256, 0, stream>>>(emb, es);
    vq_main<<<N_ROWS / BR, 256, 0, stream>>>(z, emb, es, out, lacc);
    finalize_kernel<<<1, 1, 0, stream>>>(lacc, out);
}

// Round 5
// 503.055 us; speedup vs baseline: 1.7299x; 1.7299x over previous
//
#include <hip/hip_runtime.h>
#include <math.h>

#define NR 65536
#define KE 8192
#define DD 64
#define BR 128            // rows per block
#define KT 64             // candidates per k-tile
#define NT (KE / KT)      // 128 tiles
#define TILE_BYTES 16640  // 64*256 (bf16 hi/lo frags) + 256 (e_sq floats)
#define MARGIN 6.0e-5f

typedef __attribute__((ext_vector_type(8)))  short          bf16x8;   // 8 bf16 as i16 (guide §3)
typedef __attribute__((ext_vector_type(8)))  unsigned short ushort8;
typedef __attribute__((ext_vector_type(16))) float          f32x16;

template<int P> struct IC { static constexpr int value = P; };

__device__ __forceinline__ unsigned short f2bf(float f) {
    unsigned u = __float_as_uint(f);
    u += 0x7FFF + ((u >> 16) & 1);            // RNE to bf16
    return (unsigned short)(u >> 16);
}
__device__ __forceinline__ float bf2f(unsigned short h) {
    return __uint_as_float(((unsigned)h) << 16);
}

// ---------- prep: build swizzled bf16 hi/lo image of emb (+ e_sq) in ws ----------
// Per tile t (64 cands): cand c row = 256B = 16 slots of 16B.
// keff 0..63 = e_hi[d], 64..127 = e_lo[d]; slot s16 = keff>>3, stored at s16^(c&15).
__global__ void e2_prep(const float* __restrict__ emb, char* __restrict__ e2) {
    int k = blockIdx.x * 4 + (threadIdx.x >> 6);
    int d = threadIdx.x & 63;
    float v = emb[(size_t)k * DD + d];
    unsigned short hu = f2bf(v);
    unsigned short lu = f2bf(v - bf2f(hu));
    int tile = k >> 6, c = k & 63;
    char* tb = e2 + (size_t)tile * TILE_BYTES;
    int sh = (d >> 3) ^ (c & 15);
    int sl = (8 + (d >> 3)) ^ (c & 15);
    *(unsigned short*)(tb + c * 256 + (sh << 4) + (d & 7) * 2) = hu;
    *(unsigned short*)(tb + c * 256 + (sl << 4) + (d & 7) * 2) = lu;
    // e_sq: butterfly order (bit-matched reference in round 1)
    float s = v * v;
    #pragma unroll
    for (int off = 32; off >= 1; off >>= 1) s += __shfl_down(s, off, 64);
    if (d == 0) *(float*)(tb + 16384 + c * 4) = s;
}

// ---------------- main VQ kernel ----------------
__global__ __launch_bounds__(256, 2)
void vq_main(const float* __restrict__ z, const float* __restrict__ emb,
             const char* __restrict__ e2, float* __restrict__ out,
             double* __restrict__ loss_acc)
{
    __shared__ float zbuf[BR * DD];                    // fp32 z tile, 16B-slot swizzled
    __shared__ __align__(16) char ebuf[2][TILE_BYTES]; // double-buffered emb tile image
    __shared__ float zs_best[BR];                      // z_sq per row; reused as bestk(int)

    const int tid  = threadIdx.x;
    const int w    = tid >> 6;
    const int lane = tid & 63;
    const int h    = lane >> 5;
    const int c31  = lane & 31;
    const int m0   = blockIdx.x * BR;

    auto stage = [&](int t) {   // exactly 5 global_load_lds per wave
        const char* src = e2 + (size_t)t * TILE_BYTES;
        char* dst = ebuf[t & 1];
        #pragma unroll
        for (int i = 0; i < 4; ++i) {
            int off = w * 4096 + i * 1024;
            __builtin_amdgcn_global_load_lds(
                (const __attribute__((address_space(1))) void*)(src + off + lane * 16),
                (__attribute__((address_space(3))) void*)(dst + off), 16, 0, 0);
        }
        if (lane < 16) {  // es floats: wave w copies its 64B (lanes 0..15)
            __builtin_amdgcn_global_load_lds(
                (const __attribute__((address_space(1))) void*)(src + 16384 + w * 64 + lane * 4),
                (__attribute__((address_space(3))) void*)(dst + 16384 + w * 64), 4, 0, 0);
        }
    };

    stage(0);   // overlap tile-0 fetch with z staging

    // ---- stage z tile into swizzled LDS ----
    const float4* zg = (const float4*)(z + (size_t)m0 * DD);
    #pragma unroll
    for (int i = 0; i < 8; ++i) {
        int idx = i * 256 + tid;               // 0..2047 = row*16 + slot
        int row = idx >> 4, slot = idx & 15;
        float4 v = zg[idx];
        *(float4*)&zbuf[row * DD + ((slot ^ (row & 15)) << 2)] = v;
    }
    __syncthreads();

    // ---- z_sq per row: sequential fmaf chain (round-1 bit-matched order) ----
    if (tid < BR) {
        int rsw = tid & 15, rb = tid * DD;
        float s = 0.f;
        #pragma unroll
        for (int d = 0; d < DD; ++d) {
            float v = zbuf[rb + (((d >> 2) ^ rsw) << 2) + (d & 3)];
            s = fmaf(v, v, s);
        }
        zs_best[tid] = s;
    }

    // ---- A fragments: this lane's z row, hi/lo bf16, global d = s*16 + h*8 + j ----
    const int wrow0 = w * 32;
    const int arow  = wrow0 + c31;
    const int arb   = arow * DD;
    const int asw   = arow & 15;
    bf16x8 ah[4], al[4];
    #pragma unroll
    for (int s = 0; s < 4; ++s) {
        int sl0 = s * 4 + h * 2;
        float4 f0 = *(const float4*)&zbuf[arb + ((sl0 ^ asw) << 2)];
        float4 f1 = *(const float4*)&zbuf[arb + (((sl0 + 1) ^ asw) << 2)];
        float f[8] = {f0.x, f0.y, f0.z, f0.w, f1.x, f1.y, f1.z, f1.w};
        ushort8 hu, lu;
        #pragma unroll
        for (int j = 0; j < 8; ++j) {
            unsigned short hh = f2bf(f[j]);
            hu[j] = hh;
            lu[j] = f2bf(f[j] - bf2f(hh));
        }
        ah[s] = __builtin_bit_cast(bf16x8, hu);
        al[s] = __builtin_bit_cast(bf16x8, lu);
    }
    __syncthreads();   // zs_best visible to all waves

    float bmin[16], thr[16], bef[16];
    int   bi[16];
    #pragma unroll
    for (int r = 0; r < 16; ++r) { bmin[r] = INFINITY; thr[r] = 0.f; bef[r] = INFINITY; bi[r] = 0; }

    // ---- two passes over all tiles; raw s_barrier keeps stage loads in flight ----
    auto pass_loop = [&](auto PC) {
        constexpr int PASS = decltype(PC)::value;
        for (int t = 0; t < NT; ++t) {
            if (PASS == 0 || t + 1 < NT) {
                stage((t + 1) & (NT - 1));   // pass1 t=127 prefetches tile 0 for pass 2
                asm volatile("s_waitcnt vmcnt(5)" ::: "memory");  // my stage(t) landed
            } else {
                asm volatile("s_waitcnt vmcnt(0)" ::: "memory");
            }
            __builtin_amdgcn_sched_barrier(0);
            __builtin_amdgcn_s_barrier();    // all waves' stage(t) landed
            __builtin_amdgcn_sched_barrier(0);

            const char*  eb  = ebuf[t & 1];
            const float* esp = (const float*)(eb + 16384);
            #pragma unroll
            for (int ct = 0; ct < 2; ++ct) {
                int c = ct * 32 + c31;
                const char* rowp = eb + c * 256;
                int sw = (c & 15) << 4;
                bf16x8 bh[4], bl[4];
                #pragma unroll
                for (int s = 0; s < 4; ++s) {
                    bh[s] = __builtin_bit_cast(bf16x8, *(const int4*)(rowp + (((s * 2 + h) << 4) ^ sw)));
                    bl[s] = __builtin_bit_cast(bf16x8, *(const int4*)(rowp + (((8 + s * 2 + h) << 4) ^ sw)));
                }
                f32x16 acc = {};
                #pragma unroll
                for (int s = 0; s < 4; ++s) acc = __builtin_amdgcn_mfma_f32_32x32x16_bf16(ah[s], bh[s], acc, 0, 0, 0);
                #pragma unroll
                for (int s = 0; s < 4; ++s) acc = __builtin_amdgcn_mfma_f32_32x32x16_bf16(ah[s], bl[s], acc, 0, 0, 0);
                #pragma unroll
                for (int s = 0; s < 4; ++s) acc = __builtin_amdgcn_mfma_f32_32x32x16_bf16(al[s], bh[s], acc, 0, 0, 0);

                float es_c = esp[c];
                if constexpr (PASS == 0) {
                    // cheap: track lane-local approx min only
                    #pragma unroll
                    for (int r = 0; r < 16; ++r)
                        bmin[r] = fminf(bmin[r], fmaf(-2.0f, acc[r], es_c));
                } else {
                    int cand = t * KT + c;
                    bool anyp = false;
                    #pragma unroll
                    for (int r = 0; r < 16; ++r)
                        anyp |= (fmaf(-2.0f, acc[r], es_c) < thr[r]);
                    if (__any(anyp)) {   // ~15% of (t,ct) slots
                        #pragma unroll
                        for (int r = 0; r < 16; ++r) {
                            float a2 = fmaf(-2.0f, acc[r], es_c);
                            if (a2 < thr[r]) {
                                // exact fp32 rescore, reference-matching op order
                                int row_l = wrow0 + (r & 3) + 8 * (r >> 2) + 4 * h;
                                const float4* ew4 = (const float4*)(emb + (size_t)cand * DD);
                                int zb = row_l * DD, zsw = row_l & 15;
                                float dot = 0.f;
                                #pragma unroll
                                for (int g = 0; g < 2; ++g) {
                                    float4 e4[8], z4[8];
                                    #pragma unroll
                                    for (int j = 0; j < 8; ++j) {
                                        int sl = g * 8 + j;
                                        e4[j] = ew4[sl];
                                        z4[j] = *(const float4*)&zbuf[zb + ((sl ^ zsw) << 2)];
                                    }
                                    #pragma unroll
                                    for (int j = 0; j < 8; ++j) {
                                        dot = fmaf(z4[j].x, e4[j].x, dot);
                                        dot = fmaf(z4[j].y, e4[j].y, dot);
                                        dot = fmaf(z4[j].z, e4[j].z, dot);
                                        dot = fmaf(z4[j].w, e4[j].w, dot);
                                    }
                                }
                                float ex = fmaf(-2.0f, dot, zs_best[row_l]) + es_c;
                                if (ex < bef[r]) { bef[r] = ex; bi[r] = cand; }
                            }
                        }
                    }
                }
            }
            __builtin_amdgcn_sched_barrier(0);
            __builtin_amdgcn_s_barrier();    // all waves done reading ebuf[t&1]
            __builtin_amdgcn_sched_barrier(0);
        }
    };

    pass_loop(IC<0>{});

    // ---- per-row approx-min across the 32 lanes -> pass-2 threshold ----
    #pragma unroll
    for (int r = 0; r < 16; ++r) {
        float v = bmin[r];
        #pragma unroll
        for (int off = 1; off < 32; off <<= 1) v = fminf(v, __shfl_xor(v, off, 32));
        thr[r] = v + MARGIN;
    }

    pass_loop(IC<1>{});

    // ---- cross-lane argmin reduce (exact values, first-index tie-break) ----
    int* bestk = (int*)zs_best;
    #pragma unroll
    for (int r = 0; r < 16; ++r) {
        float v = bef[r]; int ix = bi[r];
        #pragma unroll
        for (int off = 1; off < 32; off <<= 1) {
            float ov = __shfl_xor(v, off, 32);
            int   oi = __shfl_xor(ix, off, 32);
            if (ov < v || (ov == v && oi < ix)) { v = ov; ix = oi; }
        }
        if (c31 == 0) bestk[wrow0 + (r & 3) + 8 * (r >> 2) + 4 * h] = ix;
    }
    __syncthreads();

    // ---- epilogue: straight-through write, loss, indices ----
    double ls = 0.0;
    int tx = tid & 15, ty = tid >> 4;
    #pragma unroll
    for (int i = 0; i < 8; ++i) {
        int r  = i * 16 + ty;
        int bk = bestk[r];
        float4 q  = *(const float4*)&emb[(size_t)bk * DD + tx * 4];
        float4 zv = *(const float4*)&zbuf[r * DD + ((tx ^ (r & 15)) << 2)];
        float4 o;
        o.x = zv.x + (q.x - zv.x);
        o.y = zv.y + (q.y - zv.y);
        o.z = zv.z + (q.z - zv.z);
        o.w = zv.w + (q.w - zv.w);
        *(float4*)&out[(size_t)(m0 + r) * DD + tx * 4] = o;
        float ax = zv.x - q.x, ay = zv.y - q.y, az = zv.z - q.z, aw = zv.w - q.w;
        ls += (double)(ax * ax) + (double)(ay * ay) + (double)(az * az) + (double)(aw * aw);
    }
    if (tid < BR) out[(size_t)NR * DD + 2 + m0 + tid] = (float)bestk[tid];
    #pragma unroll
    for (int off = 32; off >= 1; off >>= 1) ls += __shfl_down(ls, off, 64);
    if (lane == 0) atomicAdd(loss_acc, ls);
}

// ---------------- finalize losses ----------------
__global__ void finalize_kernel(const double* __restrict__ acc, float* __restrict__ out) {
    double m = *acc / (double)((size_t)NR * DD);
    out[(size_t)NR * DD]     = (float)m;  // vq_loss
    out[(size_t)NR * DD + 1] = (float)m;  // commitment_loss
}

extern "C" void kernel_launch(void* const* d_in, const int* in_sizes, int n_in,
                              void* d_out, int out_size, void* d_ws, size_t ws_size,
                              hipStream_t stream) {
    const float* z   = (const float*)d_in[0];
    const float* emb = (const float*)d_in[1];
    float* out = (float*)d_out;

    double* lacc = (double*)d_ws;
    char*   e2   = (char*)d_ws + 256;

    hipMemsetAsync(d_ws, 0, 16, stream);
    e2_prep<<<KE / 4, 256, 0, stream>>>(emb, e2);
    vq_main<<<NR / BR, 256, 0, stream>>>(z, emb, e2, out, lacc);
    finalize_kernel<<<1, 1, 0, stream>>>(lacc, out);
}

// Round 7
// 355.002 us; speedup vs baseline: 2.4513x; 1.4170x over previous
//
#include <hip/hip_runtime.h>
#include <math.h>

#define NR 65536
#define KE 8192
#define DD 64
#define BR 128            // rows per block
#define KT 64             // candidates per k-tile
#define NT (KE / KT)      // 128 tiles
#define TILE_BYTES 8448   // 64*128 (e_hi bf16, swizzled) + 256 (e_sq floats)
#define MARGIN 3.0e-4f
#define QMAX 6144

typedef __attribute__((ext_vector_type(8)))  short          bf16x8;
typedef __attribute__((ext_vector_type(8)))  unsigned short ushort8;
typedef __attribute__((ext_vector_type(16))) float          f32x16;

template<int P> struct IC { static constexpr int value = P; };

__device__ __forceinline__ unsigned short f2bf(float f) {
    unsigned u = __float_as_uint(f);
    u += 0x7FFF + ((u >> 16) & 1);            // RNE to bf16
    return (unsigned short)(u >> 16);
}

// ---------- prep: swizzled bf16(e_hi) image of emb (+ e_sq) in ws ----------
// Per tile (64 cands): cand row = 128B = 8 slots of 16B; slot (d>>3) stored at (d>>3)^(c&7).
__global__ void e2_prep(const float* __restrict__ emb, char* __restrict__ e2) {
    int k = blockIdx.x * 4 + (threadIdx.x >> 6);
    int d = threadIdx.x & 63;
    float v = emb[(size_t)k * DD + d];
    unsigned short hu = f2bf(v);
    int tile = k >> 6, c = k & 63;
    char* tb = e2 + (size_t)tile * TILE_BYTES;
    int slot = (d >> 3) ^ (c & 7);
    *(unsigned short*)(tb + c * 128 + (slot << 4) + (d & 7) * 2) = hu;
    // e_sq: butterfly order (bit-matched reference, rounds 1 & 5)
    float s = v * v;
    #pragma unroll
    for (int off = 32; off >= 1; off >>= 1) s += __shfl_down(s, off, 64);
    if (d == 0) *(float*)(tb + 8192 + c * 4) = s;
}

// ---------------- main VQ kernel ----------------
__global__ __launch_bounds__(256, 2)
void vq_main(const float* __restrict__ z, const float* __restrict__ emb,
             const char* __restrict__ e2, float* __restrict__ out,
             double* __restrict__ loss_acc)
{
    __shared__ float zbuf[BR * DD];                    // fp32 z tile, 16B-slot swizzled
    __shared__ __align__(16) char ebuf[2][TILE_BYTES]; // double-buffered emb tile image
    __shared__ float zs[BR];                           // z_sq per row
    __shared__ unsigned long long best64[BR];          // packed (F_bits<<32)|cand per row
    __shared__ unsigned qbuf[QMAX];                    // rescore queue: (row<<13)|cand
    __shared__ int qn;

    const int tid  = threadIdx.x;
    const int w    = tid >> 6;
    const int lane = tid & 63;
    const int h    = lane >> 5;
    const int c31  = lane & 31;
    const int m0   = blockIdx.x * BR;

    auto stage = [&](int t) {   // exactly 3 global_load_lds per wave
        const char* src = e2 + (size_t)t * TILE_BYTES;
        char* dst = ebuf[t & 1];
        #pragma unroll
        for (int i = 0; i < 2; ++i) {
            int off = w * 2048 + i * 1024;
            __builtin_amdgcn_global_load_lds(
                (const __attribute__((address_space(1))) void*)(src + off + lane * 16),
                (__attribute__((address_space(3))) void*)(dst + off), 16, 0, 0);
        }
        if (lane < 16) {  // es floats: wave w copies its 64B
            __builtin_amdgcn_global_load_lds(
                (const __attribute__((address_space(1))) void*)(src + 8192 + w * 64 + lane * 4),
                (__attribute__((address_space(3))) void*)(dst + 8192 + w * 64), 4, 0, 0);
        }
    };

    stage(0);   // overlap tile-0 fetch with z staging

    // ---- stage z tile into swizzled LDS ----
    const float4* zg = (const float4*)(z + (size_t)m0 * DD);
    #pragma unroll
    for (int i = 0; i < 8; ++i) {
        int idx = i * 256 + tid;               // 0..2047 = row*16 + slot
        int row = idx >> 4, slot = idx & 15;
        float4 v = zg[idx];
        *(float4*)&zbuf[row * DD + ((slot ^ (row & 15)) << 2)] = v;
    }
    __syncthreads();

    // ---- z_sq per row: sequential fmaf chain (bit-matched order, rounds 1/5) ----
    if (tid < BR) {
        int rsw = tid & 15, rb = tid * DD;
        float s = 0.f;
        #pragma unroll
        for (int d = 0; d < DD; ++d) {
            float v = zbuf[rb + (((d >> 2) ^ rsw) << 2) + (d & 3)];
            s = fmaf(v, v, s);
        }
        zs[tid] = s;
    }

    // ---- A fragments: this lane's z row (hi only), global d = s*16 + h*8 + j ----
    const int wrow0 = w * 32;
    const int arow  = wrow0 + c31;
    const int arb   = arow * DD;
    const int asw   = arow & 15;
    bf16x8 ah[4];
    #pragma unroll
    for (int s = 0; s < 4; ++s) {
        int sl0 = s * 4 + h * 2;
        float4 f0 = *(const float4*)&zbuf[arb + ((sl0 ^ asw) << 2)];
        float4 f1 = *(const float4*)&zbuf[arb + (((sl0 + 1) ^ asw) << 2)];
        float f[8] = {f0.x, f0.y, f0.z, f0.w, f1.x, f1.y, f1.z, f1.w};
        ushort8 hu;
        #pragma unroll
        for (int j = 0; j < 8; ++j) hu[j] = f2bf(f[j]);
        ah[s] = __builtin_bit_cast(bf16x8, hu);
    }
    __syncthreads();   // zs visible to all waves

    // exact fp32 rescore (reference op order) + packed atomicMin on row best
    auto exact_upd = [&](int row_l, int cand, float es_c) {
        const float4* ew4 = (const float4*)(emb + (size_t)cand * DD);
        int zb = row_l * DD, zsw = row_l & 15;
        float dot = 0.f;
        #pragma unroll
        for (int sl = 0; sl < 16; ++sl) {
            float4 e4 = ew4[sl];
            float4 z4 = *(const float4*)&zbuf[zb + ((sl ^ zsw) << 2)];
            dot = fmaf(z4.x, e4.x, dot);
            dot = fmaf(z4.y, e4.y, dot);
            dot = fmaf(z4.z, e4.z, dot);
            dot = fmaf(z4.w, e4.w, dot);
        }
        float F = fmaf(-2.0f, dot, zs[row_l]) + es_c;
        unsigned long long pk =
            ((unsigned long long)__float_as_uint(F) << 32) | (unsigned)cand;
        atomicMin(&best64[row_l], pk);
    };

    float bmin[16];   // pass-1: lane-local approx min; becomes thr after reduce
    #pragma unroll
    for (int r = 0; r < 16; ++r) bmin[r] = INFINITY;

    auto pass_loop = [&](auto PC) {
        constexpr int PASS = decltype(PC)::value;
        for (int t = 0; t < NT; ++t) {
            if (PASS == 0 || t + 1 < NT) {
                stage((t + 1) & (NT - 1));   // pass1 t=127 prefetches tile 0 for pass 2
                asm volatile("s_waitcnt vmcnt(3)" ::: "memory");  // my stage(t) landed
            } else {
                asm volatile("s_waitcnt vmcnt(0)" ::: "memory");
            }
            __builtin_amdgcn_sched_barrier(0);
            __builtin_amdgcn_s_barrier();    // all waves' stage(t) landed
            __builtin_amdgcn_sched_barrier(0);

            const char*  eb  = ebuf[t & 1];
            const float* esp = (const float*)(eb + 8192);
            #pragma unroll
            for (int ct = 0; ct < 2; ++ct) {
                int c = ct * 32 + c31;
                const char* rowp = eb + c * 128;
                int sw7 = c & 7;
                bf16x8 bh[4];
                #pragma unroll
                for (int s = 0; s < 4; ++s)
                    bh[s] = __builtin_bit_cast(bf16x8, *(const int4*)(rowp + (((s * 2 + h) ^ sw7) << 4)));
                f32x16 acc = {};
                #pragma unroll
                for (int s = 0; s < 4; ++s)
                    acc = __builtin_amdgcn_mfma_f32_32x32x16_bf16(ah[s], bh[s], acc, 0, 0, 0);

                float es_c = esp[c];
                if constexpr (PASS == 0) {
                    #pragma unroll
                    for (int r = 0; r < 16; ++r)
                        bmin[r] = fminf(bmin[r], fmaf(-2.0f, acc[r], es_c));
                } else {
                    int cand = t * KT + c;
                    bool anyp = false;
                    #pragma unroll
                    for (int r = 0; r < 16; ++r)
                        anyp |= (fmaf(-2.0f, acc[r], es_c) < bmin[r]);
                    if (__any(anyp)) {   // rare slot: push admitted cands to queue
                        #pragma unroll
                        for (int r = 0; r < 16; ++r) {
                            if (fmaf(-2.0f, acc[r], es_c) < bmin[r]) {
                                int row_l = wrow0 + (r & 3) + 8 * (r >> 2) + 4 * h;
                                int slot = atomicAdd(&qn, 1);
                                if (slot < QMAX)
                                    qbuf[slot] = ((unsigned)row_l << 13) | (unsigned)cand;
                                else
                                    exact_upd(row_l, cand, es_c);  // overflow fallback (correct)
                            }
                        }
                    }
                }
            }
            __builtin_amdgcn_sched_barrier(0);
            __builtin_amdgcn_s_barrier();    // all waves done reading ebuf[t&1]
            __builtin_amdgcn_sched_barrier(0);
        }
    };

    pass_loop(IC<0>{});

    // ---- per-row approx-min across 32 lanes -> threshold (reuse bmin regs) ----
    #pragma unroll
    for (int r = 0; r < 16; ++r) {
        float v = bmin[r];
        #pragma unroll
        for (int off = 1; off < 32; off <<= 1) v = fminf(v, __shfl_xor(v, off, 32));
        bmin[r] = v + MARGIN;
    }
    if (tid < BR) best64[tid] = 0xFFFFFFFFFFFFFFFFull;
    if (tid == 0) qn = 0;
    __syncthreads();

    pass_loop(IC<1>{});
    __syncthreads();   // queue + counters visible

    // ---- drain queue: batched exact rescores, no hot-loop divergence ----
    int qn_v = qn < QMAX ? qn : QMAX;
    for (int i = tid; i < qn_v; i += 256) {
        unsigned e = qbuf[i];
        int row_l = e >> 13, cand = e & 8191;
        float es_c = *(const float*)(e2 + (size_t)(cand >> 6) * TILE_BYTES + 8192 + (cand & 63) * 4);
        exact_upd(row_l, cand, es_c);
    }
    __syncthreads();

    // ---- epilogue: straight-through write, loss, indices ----
    double ls = 0.0;
    int tx = tid & 15, ty = tid >> 4;
    #pragma unroll
    for (int i = 0; i < 8; ++i) {
        int r  = i * 16 + ty;
        int bk = (int)(best64[r] & 0xFFFFFFFFu);
        float4 q  = *(const float4*)&emb[(size_t)bk * DD + tx * 4];
        float4 zv = *(const float4*)&zbuf[r * DD + ((tx ^ (r & 15)) << 2)];
        float4 o;
        o.x = zv.x + (q.x - zv.x);
        o.y = zv.y + (q.y - zv.y);
        o.z = zv.z + (q.z - zv.z);
        o.w = zv.w + (q.w - zv.w);
        *(float4*)&out[(size_t)(m0 + r) * DD + tx * 4] = o;
        float ax = zv.x - q.x, ay = zv.y - q.y, az = zv.z - q.z, aw = zv.w - q.w;
        ls += (double)(ax * ax) + (double)(ay * ay) + (double)(az * az) + (double)(aw * aw);
    }
    if (tid < BR) out[(size_t)NR * DD + 2 + m0 + tid] = (float)(best64[tid] & 0xFFFFFFFFu);
    #pragma unroll
    for (int off = 32; off >= 1; off >>= 1) ls += __shfl_down(ls, off, 64);
    if (lane == 0) atomicAdd(loss_acc, ls);
}

// ---------------- finalize losses ----------------
__global__ void finalize_kernel(const double* __restrict__ acc, float* __restrict__ out) {
    double m = *acc / (double)((size_t)NR * DD);
    out[(size_t)NR * DD]     = (float)m;  // vq_loss
    out[(size_t)NR * DD + 1] = (float)m;  // commitment_loss
}

extern "C" void kernel_launch(void* const* d_in, const int* in_sizes, int n_in,
                              void* d_out, int out_size, void* d_ws, size_t ws_size,
                              hipStream_t stream) {
    const float* z   = (const float*)d_in[0];
    const float* emb = (const float*)d_in[1];
    float* out = (float*)d_out;

    double* lacc = (double*)d_ws;
    char*   e2   = (char*)d_ws + 256;

    hipMemsetAsync(d_ws, 0, 16, stream);
    e2_prep<<<KE / 4, 256, 0, stream>>>(emb, e2);
    vq_main<<<NR / BR, 256, 0, stream>>>(z, emb, e2, out, lacc);
    finalize_kernel<<<1, 1, 0, stream>>>(lacc, out);
}